// Round 6
// baseline (2765.683 us; speedup 1.0000x reference)
//
#include <hip/hip_runtime.h>

// SimpleARRNN: GRU encoder (len<=512) + AR decoder (257 outputs). B=512, I=64, H=100, O=64. fp32.
// Fused affine input paths: W_c = W_ih@W_embed [300x64], b_c = W_ih@b_embed + b_ih
//                           W_d = W_c@W_proj   [300x100], b_d = W_c@b_proj + b_c
// rnn6: 2 elements/block (long+short pair via length sort), 256 blocks x 1024 threads.
// 4-lane row split: group g = tid>>2 (0..255), lane l = tid&3 owns cols 25l..25l+24 (exactly
// 100 = 4x25, no masks). 3 passes, slot = 256p + g covers 768 >= 664 rows:
//   decoder rows: 0..299 Whh (gh) | 300..599 Wd (xi) | 600..663 Wproj -> sdot[e][slot]
//   encoder rows: 0..299 Whh (gh, K=100 from h) | 300..599 Wc (xi, K=64 from ctx, 16 cols/lane)
// Reduce = DPP quad_perm xor1 (0xB1) + xor2 (0x4E) (involutions, verified R5); lane0 stores.
// h in LDS at chunk stride 28 (112 B, b128-aligned; banks 0/28/24/20 disjoint per beat).
// amdgpu_num_vgpr(128): R5 showed waves_per_eu(4,4) alone split the 128-budget as 64 VGPR
// + 64 AGPR -> v_accvgpr moves per weight use; this requests the full 128 as arch VGPRs.

#define B_  512
#define LC_ 512
#define I_  64
#define H_  100
#define O_  64
#define T_  256
#define H3  300

// ws float offsets
#define WS_WC   0        // [300][64]
#define WS_BC   19200    // [300]
#define WS_WD   19500    // [300][100]
#define WS_BD   49500    // [300]
#define WS_PERM 49800    // int[512]

__global__ __launch_bounds__(64) void prep1(const float* __restrict__ Wih,
                                            const float* __restrict__ bih,
                                            const float* __restrict__ Wemb,
                                            const float* __restrict__ bemb,
                                            float* __restrict__ ws) {
    int j = blockIdx.x;   // 0..299
    int i = threadIdx.x;  // 0..63
    float acc = 0.f;
    for (int k = 0; k < H_; ++k) acc += Wih[j * H_ + k] * Wemb[k * I_ + i];
    ws[WS_WC + j * I_ + i] = acc;
    if (i == 0) {
        float b = bih[j];
        for (int k = 0; k < H_; ++k) b += Wih[j * H_ + k] * bemb[k];
        ws[WS_BC + j] = b;
    }
}

__global__ __launch_bounds__(128) void prep2(const float* __restrict__ Wproj,
                                             const float* __restrict__ bproj,
                                             float* __restrict__ ws) {
    int j = blockIdx.x;   // 0..299
    int u = threadIdx.x;
    const float* Wc = ws + WS_WC;
    if (u < H_) {
        float acc = 0.f;
        for (int o = 0; o < O_; ++o) acc += Wc[j * I_ + o] * Wproj[o * H_ + u];
        ws[WS_WD + j * H_ + u] = acc;
    }
    if (u == 0) {
        float b = ws[WS_BC + j];
        for (int o = 0; o < O_; ++o) b += Wc[j * I_ + o] * bproj[o];
        ws[WS_BD + j] = b;
    }
}

// rank elements by length descending -> perm (longest first)
__global__ __launch_bounds__(512) void sortk(const int* __restrict__ lens,
                                             int* __restrict__ perm) {
    __shared__ int sl[B_];
    int tid = threadIdx.x;
    sl[tid] = lens[tid];
    __syncthreads();
    int li = sl[tid];
    int rank = 0;
    for (int j = 0; j < B_; ++j) {
        int lj = sl[j];
        rank += (lj > li) || (lj == li && j < tid);
    }
    perm[rank] = tid;
}

__device__ __forceinline__ float sigm_(float x) { return 1.f / (1.f + __expf(-x)); }
__device__ __forceinline__ float tanh_(float x) {
    float t = __expf(-2.f * fabsf(x));
    float r = (1.f - t) / (1.f + t);
    return (x >= 0.f) ? r : -r;
}

template <int CTRL>
__device__ __forceinline__ float dppmov_(float x) {
    return __int_as_float(
        __builtin_amdgcn_mov_dpp(__float_as_int(x), CTRL, 0xF, 0xF, true));
}
// sum over 4 contiguous lanes (one row group); full butterfly, valid in all 4 lanes
__device__ __forceinline__ float red4_(float a) {
    a += dppmov_<0xB1>(a);    // quad_perm [1,0,3,2]  (xor 1)
    a += dppmov_<0x4E>(a);    // quad_perm [2,3,0,1]  (xor 2)
    return a;
}

__device__ __forceinline__ float dot25_(const float* __restrict__ w, const float* __restrict__ v) {
    float a0 = 0.f, a1 = 0.f;
    #pragma unroll
    for (int j = 0; j < 12; ++j) a0 = fmaf(w[j], v[j], a0);
    #pragma unroll
    for (int j = 12; j < 25; ++j) a1 = fmaf(w[j], v[j], a1);
    return a0 + a1;
}
__device__ __forceinline__ float dot16_(const float* __restrict__ w, const float* __restrict__ v) {
    float a0 = 0.f, a1 = 0.f;
    #pragma unroll
    for (int j = 0; j < 8; ++j) a0 = fmaf(w[j], v[j], a0);
    #pragma unroll
    for (int j = 8; j < 16; ++j) a1 = fmaf(w[j], v[j], a1);
    return a0 + a1;
}

__global__ __attribute__((amdgpu_flat_work_group_size(1024, 1024)))
__attribute__((amdgpu_waves_per_eu(4, 4)))
__attribute__((amdgpu_num_vgpr(128)))
void rnn6(const float* __restrict__ ctx, const int* __restrict__ lens,
          const float* __restrict__ Whh, const float* __restrict__ bhh,
          const float* __restrict__ Wproj, const float* __restrict__ bproj,
          const float* __restrict__ ws, float* __restrict__ out) {

    const int tid = threadIdx.x;
    const int l   = tid & 3;          // lane-slice within row (25 cols)
    const int g   = tid >> 2;         // 0..255 row-group
    const int eh  = tid >> 9;         // element served by this thread's gate/io half
    const int idx = tid & 511;
    const bool wl = (l == 0);

    const int* perm = (const int*)(ws + WS_PERM);
    const int e0 = perm[blockIdx.x];         // long element
    const int e1 = perm[511 - blockIdx.x];   // short element
    const int len0 = lens[e0], len1 = lens[e1];
    const int eMy = eh ? e1 : e0;
    const int lenMy = eh ? len1 : len0;

    __shared__ __align__(16) float sh[2][112];    // h: 4 chunks of 25, stride 28 (b128-aligned)
    __shared__ __align__(16) float sctx[2][64];
    __shared__ float sdot[2][672];                // gh 0..299 | xi 300..599 | proj 600..663
    __shared__ float sbh[H3], sbx[H3];

    // ---- thread-static pass config ----
    const int s0 = g, s1 = 256 + g, s2 = 512 + g;
    const bool eH1 = (s1 < H3);                 // pass1 encoder: gh rows 300.. boundary
    const bool eC1 = (s1 >= H3);                // pass1 encoder ctx-dot (s1<512+..<600 always true)
    const bool eC2 = (s2 < 600);                // pass2 encoder ctx-dot
    const bool dA1 = true;                      // pass1 decoder always active (s1<512<664)
    const bool dA2 = (s2 < 664);                // pass2 decoder active

    float w[3][25];   // per-pass weights (cols 25l..), encoder ctx rows use first 16

    // ---- load ENCODER weights ----
    {
        #pragma unroll
        for (int j = 0; j < 25; ++j) w[0][j] = Whh[s0 * H_ + 25 * l + j];   // pass0: always Whh
        if (eH1) {
            #pragma unroll
            for (int j = 0; j < 25; ++j) w[1][j] = Whh[s1 * H_ + 25 * l + j];
        } else {
            #pragma unroll
            for (int j = 0; j < 16; ++j) w[1][j] = (ws + WS_WC)[(s1 - H3) * I_ + 16 * l + j];
        }
        if (eC2) {
            #pragma unroll
            for (int j = 0; j < 16; ++j) w[2][j] = (ws + WS_WC)[(s2 - H3) * I_ + 16 * l + j];
        }
    }

    // ---- init ----
    if (tid < 224) ((float*)sh)[tid] = 0.f;
    if (tid < H3) { sbh[tid] = bhh[tid]; sbx[tid] = (ws + WS_BC)[tid]; }
    const float4* ctxe = (const float4*)(ctx + (size_t)eMy * LC_ * I_);
    if (idx < 16) *(float4*)&sctx[eh][4 * idx] = ctxe[idx];   // t=0
    float bpr = 0.f;
    if (idx >= 128 && idx < 192) bpr = bproj[idx - 128];
    float hreg = 0.f;
    const int hq = 28 * (idx / 25) + (idx % 25);   // gate write slot (idx<100)
    __syncthreads();

    // ================ encoder: t = 0 .. len0-1 (len0 >= len1) ================
    for (int t = 0; t < len0; ++t) {
        float4 pf;
        const bool havepf = (idx < 16) && (t + 1 < lenMy);
        if (havepf) pf = ctxe[(t + 1) * 16 + idx];

        #pragma unroll
        for (int e = 0; e < 2; ++e) {
            if (e == 0 || t < len1) {       // block-uniform skip of finished element
                float hv[25], cv[16];
                *(float4*)&hv[0]  = *(const float4*)&sh[e][28 * l];
                *(float4*)&hv[4]  = *(const float4*)&sh[e][28 * l + 4];
                *(float4*)&hv[8]  = *(const float4*)&sh[e][28 * l + 8];
                *(float4*)&hv[12] = *(const float4*)&sh[e][28 * l + 12];
                *(float4*)&hv[16] = *(const float4*)&sh[e][28 * l + 16];
                *(float4*)&hv[20] = *(const float4*)&sh[e][28 * l + 20];
                hv[24] = sh[e][28 * l + 24];
                *(float4*)&cv[0]  = *(const float4*)&sctx[e][16 * l];
                *(float4*)&cv[4]  = *(const float4*)&sctx[e][16 * l + 4];
                *(float4*)&cv[8]  = *(const float4*)&sctx[e][16 * l + 8];
                *(float4*)&cv[12] = *(const float4*)&sctx[e][16 * l + 12];

                float a0 = red4_(dot25_(w[0], hv));                       // gh row s0
                float a1 = eH1 ? red4_(dot25_(w[1], hv))                  // gh row s1
                               : red4_(dot16_(w[1], cv));                 // xi row s1-300
                float a2 = eC2 ? red4_(dot16_(w[2], cv)) : 0.f;           // xi row s2-300
                if (wl) {
                    sdot[e][s0] = a0;
                    sdot[e][s1] = a1;
                    if (eC2) sdot[e][s2] = a2;
                }
            }
        }
        __syncthreads();
        if (idx < H_ && t < lenMy) {
            const float* sd = sdot[eh];
            float gr = sd[idx]       + sbh[idx];
            float gz = sd[idx + 100] + sbh[idx + 100];
            float gn = sd[idx + 200] + sbh[idx + 200];
            float xr = sd[idx + 300] + sbx[idx];
            float xz = sd[idx + 400] + sbx[idx + 100];
            float xn = sd[idx + 500] + sbx[idx + 200];
            float r = sigm_(xr + gr);
            float z = sigm_(xz + gz);
            float n = tanh_(xn + r * gn);
            hreg = (1.f - z) * n + z * hreg;
            sh[eh][hq] = hreg;
        }
        if (havepf) *(float4*)&sctx[eh][4 * idx] = pf;
        __syncthreads();
    }

    // ---- switch to DECODER weights: rows 0..299 Whh | 300..599 Wd | 600..663 Wproj ----
    {
        if (!eH1) {
            #pragma unroll
            for (int j = 0; j < 25; ++j) w[1][j] = (ws + WS_WD)[(s1 - H3) * H_ + 25 * l + j];
        }
        if (s2 < 600) {
            #pragma unroll
            for (int j = 0; j < 25; ++j) w[2][j] = (ws + WS_WD)[(s2 - H3) * H_ + 25 * l + j];
        } else if (s2 < 664) {
            #pragma unroll
            for (int j = 0; j < 25; ++j) w[2][j] = Wproj[(s2 - 600) * H_ + 25 * l + j];
        }
    }
    if (tid < H3) sbx[tid] = (ws + WS_BD)[tid];
    // safe: sbx next read only after the decoder's first __syncthreads()

    // ================ decoder: outputs t = 0..256 ================
    float* oute = out + (size_t)eMy * (T_ + 1) * O_;
    for (int t = 0; t <= T_; ++t) {
        #pragma unroll
        for (int e = 0; e < 2; ++e) {
            float hv[25];
            *(float4*)&hv[0]  = *(const float4*)&sh[e][28 * l];
            *(float4*)&hv[4]  = *(const float4*)&sh[e][28 * l + 4];
            *(float4*)&hv[8]  = *(const float4*)&sh[e][28 * l + 8];
            *(float4*)&hv[12] = *(const float4*)&sh[e][28 * l + 12];
            *(float4*)&hv[16] = *(const float4*)&sh[e][28 * l + 16];
            *(float4*)&hv[20] = *(const float4*)&sh[e][28 * l + 20];
            hv[24] = sh[e][28 * l + 24];

            float a0 = red4_(dot25_(w[0], hv));
            float a1 = red4_(dot25_(w[1], hv));
            float a2 = dA2 ? red4_(dot25_(w[2], hv)) : 0.f;
            if (wl) {
                sdot[e][s0] = a0;
                sdot[e][s1] = a1;
                if (dA2) sdot[e][s2] = a2;
            }
        }
        __syncthreads();
        if (idx >= 128 && idx < 192) {
            const int o = idx - 128;
            oute[t * O_ + o] = sdot[eh][600 + o] + bpr;
        }
        if (t == T_) break;   // uniform
        if (idx < H_) {
            const float* sd = sdot[eh];
            float gr = sd[idx]       + sbh[idx];
            float gz = sd[idx + 100] + sbh[idx + 100];
            float gn = sd[idx + 200] + sbh[idx + 200];
            float xr = sd[idx + 300] + sbx[idx];
            float xz = sd[idx + 400] + sbx[idx + 100];
            float xn = sd[idx + 500] + sbx[idx + 200];
            float r = sigm_(xr + gr);
            float z = sigm_(xz + gz);
            float n = tanh_(xn + r * gn);
            hreg = (1.f - z) * n + z * hreg;
            sh[eh][hq] = hreg;
        }
        __syncthreads();
    }
}

extern "C" void kernel_launch(void* const* d_in, const int* in_sizes, int n_in,
                              void* d_out, int out_size, void* d_ws, size_t ws_size,
                              hipStream_t stream) {
    (void)in_sizes; (void)n_in; (void)out_size; (void)ws_size;
    const float* ctx  = (const float*)d_in[0];
    const int*   lens = (const int*)d_in[1];
    // d_in[2] = t_steps (256, hardcoded)
    const float* Wemb = (const float*)d_in[3];
    const float* bemb = (const float*)d_in[4];
    const float* Wih  = (const float*)d_in[5];
    const float* bih  = (const float*)d_in[6];
    const float* Whh  = (const float*)d_in[7];
    const float* bhh  = (const float*)d_in[8];
    const float* Wpr  = (const float*)d_in[9];
    const float* bpr  = (const float*)d_in[10];
    float* ws  = (float*)d_ws;
    float* out = (float*)d_out;

    prep1<<<H3, 64, 0, stream>>>(Wih, bih, Wemb, bemb, ws);
    prep2<<<H3, 128, 0, stream>>>(Wpr, bpr, ws);
    sortk<<<1, 512, 0, stream>>>(lens, (int*)(ws + WS_PERM));
    rnn6<<<256, 1024, 0, stream>>>(ctx, lens, Whh, bhh, Wpr, bpr, ws, out);
}

// Round 7
// 900.080 us; speedup vs baseline: 3.0727x; 3.0727x over previous
//
#include <hip/hip_runtime.h>

// SimpleARRNN: GRU encoder (len<=512) + AR decoder (257 outputs). B=512, I=64, H=100, O=64. fp32.
// Fused affine input paths: W_c = W_ih@W_embed [300x64], b_c = W_ih@b_embed + b_ih
//                           W_d = W_c@W_proj   [300x100], b_d = W_c@b_proj + b_c
// rnn7: 2 elements/block (long+short pair, length-sorted), 256 blocks x 512 threads,
// amdgpu_waves_per_eu(2,2): 8 waves/block = 2/EU -> 256-VGPR budget (R3-R6 lesson: at
// 1024 threads the allocator pins 64 VGPR and spills; 512 threads is the natural fit).
// 2-lane row split: g=tid>>1 owns rows {g, 256+g, 512+g}, lane l=tid&1 owns cols 50l..50l+49.
// Weights register-resident as float2 (v_pk_fma_f32: 2 fp32 FMA/instr). Reduce = one DPP
// quad_perm xor1 (involution, verified R5) + lane0 store. sdot[e]: gh 0..299 | xi 300..599 |
// proj 600..663. Roles: tid<200 gates (e=tid>=100); 256..383 out-writers; 384..415 ctx prefetch.

#define B_  512
#define LC_ 512
#define I_  64
#define H_  100
#define O_  64
#define T_  256
#define H3  300

// ws float offsets
#define WS_WC   0        // [300][64]
#define WS_BC   19200    // [300]
#define WS_WD   19500    // [300][100]
#define WS_BD   49500    // [300]
#define WS_PERM 49800    // int[512]

typedef float v2f __attribute__((ext_vector_type(2)));

__global__ __launch_bounds__(64) void prep1(const float* __restrict__ Wih,
                                            const float* __restrict__ bih,
                                            const float* __restrict__ Wemb,
                                            const float* __restrict__ bemb,
                                            float* __restrict__ ws) {
    int j = blockIdx.x;   // 0..299
    int i = threadIdx.x;  // 0..63
    float acc = 0.f;
    for (int k = 0; k < H_; ++k) acc += Wih[j * H_ + k] * Wemb[k * I_ + i];
    ws[WS_WC + j * I_ + i] = acc;
    if (i == 0) {
        float b = bih[j];
        for (int k = 0; k < H_; ++k) b += Wih[j * H_ + k] * bemb[k];
        ws[WS_BC + j] = b;
    }
}

__global__ __launch_bounds__(128) void prep2(const float* __restrict__ Wproj,
                                             const float* __restrict__ bproj,
                                             float* __restrict__ ws) {
    int j = blockIdx.x;   // 0..299
    int u = threadIdx.x;
    const float* Wc = ws + WS_WC;
    if (u < H_) {
        float acc = 0.f;
        for (int o = 0; o < O_; ++o) acc += Wc[j * I_ + o] * Wproj[o * H_ + u];
        ws[WS_WD + j * H_ + u] = acc;
    }
    if (u == 0) {
        float b = ws[WS_BC + j];
        for (int o = 0; o < O_; ++o) b += Wc[j * I_ + o] * bproj[o];
        ws[WS_BD + j] = b;
    }
}

// rank elements by length descending -> perm (longest first)
__global__ __launch_bounds__(512) void sortk(const int* __restrict__ lens,
                                             int* __restrict__ perm) {
    __shared__ int sl[B_];
    int tid = threadIdx.x;
    sl[tid] = lens[tid];
    __syncthreads();
    int li = sl[tid];
    int rank = 0;
    for (int j = 0; j < B_; ++j) {
        int lj = sl[j];
        rank += (lj > li) || (lj == li && j < tid);
    }
    perm[rank] = tid;
}

__device__ __forceinline__ float sigm_(float x) { return 1.f / (1.f + __expf(-x)); }
__device__ __forceinline__ float tanh_(float x) {
    float t = __expf(-2.f * fabsf(x));
    float r = (1.f - t) / (1.f + t);
    return (x >= 0.f) ? r : -r;
}

template <int CTRL>
__device__ __forceinline__ float dppmov_(float x) {
    return __int_as_float(
        __builtin_amdgcn_mov_dpp(__float_as_int(x), CTRL, 0xF, 0xF, true));
}

// dot over N float2 pairs + cross-lane-pair reduce; both lanes end with full row sum
template <int N>
__device__ __forceinline__ float dotred_(const v2f* __restrict__ w, const v2f* __restrict__ v) {
    v2f a = {0.f, 0.f};
    #pragma unroll
    for (int j = 0; j < N; ++j) a = w[j] * v[j] + a;   // contracts to v_pk_fma_f32
    float s = a.x + a.y;
    s += dppmov_<0xB1>(s);    // quad_perm [1,0,3,2] = xor1 (involution, verified R5)
    return s;
}

__global__ __attribute__((amdgpu_flat_work_group_size(512, 512)))
__attribute__((amdgpu_waves_per_eu(2, 2)))
void rnn7(const float* __restrict__ ctx, const int* __restrict__ lens,
          const float* __restrict__ Whh, const float* __restrict__ bhh,
          const float* __restrict__ Wproj, const float* __restrict__ bproj,
          const float* __restrict__ ws, float* __restrict__ out) {

    const int tid = threadIdx.x;
    const int l   = tid & 1;          // lane half: cols 50l..50l+49 (enc ctx: 32l..32l+31)
    const int g   = tid >> 1;         // 0..255 row-group
    const bool wl = (l == 0);

    const int* perm = (const int*)(ws + WS_PERM);
    const int e0 = perm[blockIdx.x];         // long element
    const int e1 = perm[511 - blockIdx.x];   // short element
    const int len0 = lens[e0], len1 = lens[e1];

    __shared__ __align__(16) float sh[2][104];    // h: half at 52*l (52*4B = 13x16B aligned)
    __shared__ __align__(16) float sctx[2][64];
    __shared__ float sdot[2][672];                // gh 0..299 | xi 300..599 | proj 600..663
    __shared__ float sbh[H3], sbx[H3];

    // ---- rows owned by this thread ----
    const int r0 = g;            // pass0: Whh row (both phases)
    const int r1 = 256 + g;      // pass1: g<44 -> Whh; else input-path row r1-300
    const int r2 = 512 + g;      // pass2: enc g<88 (Wc row r2-300); dec g<152 (Wd / Wproj)
    const bool p1hh = (g < 44);
    const bool p2e  = (g < 88);
    const bool p2d  = (g < 152);

    // ---- register-resident weights (float2 pairs) ----
    v2f wA[25], wB[25], wC[25];
    {
        const float* rowA = Whh + r0 * H_ + 50 * l;
        #pragma unroll
        for (int j = 0; j < 25; ++j) wA[j] = *(const v2f*)(rowA + 2 * j);
        if (p1hh) {
            const float* rowB = Whh + r1 * H_ + 50 * l;
            #pragma unroll
            for (int j = 0; j < 25; ++j) wB[j] = *(const v2f*)(rowB + 2 * j);
        } else {
            const float* rowB = ws + WS_WC + (r1 - H3) * I_ + 32 * l;
            #pragma unroll
            for (int j = 0; j < 16; ++j) wB[j] = *(const v2f*)(rowB + 2 * j);
        }
        if (p2e) {
            const float* rowC = ws + WS_WC + (r2 - H3) * I_ + 32 * l;
            #pragma unroll
            for (int j = 0; j < 16; ++j) wC[j] = *(const v2f*)(rowC + 2 * j);
        }
    }

    // ---- role setup ----
    const int ge = (tid >= 100);                 // gate threads: tid<200
    const int gi = tid - (ge ? 100 : 0);
    const int hs = (gi < 50) ? gi : gi + 2;      // h slot (52-stride halves)
    const int lenG = ge ? len1 : len0;
    float hreg = 0.f;

    const int oe = (tid >> 6) & 1;               // out threads: tid in [256,384)
    const int oo = tid & 63;
    float* oute = out + (size_t)(oe ? e1 : e0) * (T_ + 1) * O_;
    float bpr = 0.f;
    if (tid >= 256 && tid < 384) bpr = bproj[oo];

    const int pe = (tid >> 4) & 1;               // prefetch threads: tid in [384,416)
    const int pi = tid & 15;
    const float4* pctx = (const float4*)(ctx + (size_t)(pe ? e1 : e0) * LC_ * I_);
    const int lenP = pe ? len1 : len0;

    // ---- init ----
    if (tid < 208) ((float*)sh)[tid] = 0.f;
    if (tid < H3) { sbh[tid] = bhh[tid]; sbx[tid] = (ws + WS_BC)[tid]; }
    if (tid >= 384 && tid < 416) *(float4*)&sctx[pe][4 * pi] = pctx[pi];   // t=0
    __syncthreads();

    // ================ encoder: t = 0 .. len0-1 (len0 >= len1) ================
    for (int t = 0; t < len0; ++t) {
        float4 pf;
        const bool hp = (tid >= 384 && tid < 416) && (t + 1 < lenP);
        if (hp) pf = pctx[(t + 1) * 16 + pi];

        #pragma unroll
        for (int e = 0; e < 2; ++e) {
            if (e == 0 || t < len1) {       // block-uniform skip of finished element
                v2f hv[25], cv[16];
                #pragma unroll
                for (int q = 0; q < 12; ++q) {
                    float4 f = *(const float4*)&sh[e][52 * l + 4 * q];
                    hv[2 * q]     = v2f{f.x, f.y};
                    hv[2 * q + 1] = v2f{f.z, f.w};
                }
                hv[24] = *(const v2f*)&sh[e][52 * l + 48];
                #pragma unroll
                for (int q = 0; q < 8; ++q) {
                    float4 f = *(const float4*)&sctx[e][32 * l + 4 * q];
                    cv[2 * q]     = v2f{f.x, f.y};
                    cv[2 * q + 1] = v2f{f.z, f.w};
                }

                float a0 = dotred_<25>(wA, hv);
                if (wl) sdot[e][r0] = a0;
                float a1 = p1hh ? dotred_<25>(wB, hv) : dotred_<16>(wB, cv);
                if (wl) sdot[e][r1] = a1;
                if (p2e) {
                    float a2 = dotred_<16>(wC, cv);
                    if (wl) sdot[e][r2] = a2;
                }
            }
        }
        __syncthreads();
        if (tid < 200 && t < lenG) {
            const float* sd = sdot[ge];
            float gr = sd[gi]       + sbh[gi];
            float gz = sd[gi + 100] + sbh[gi + 100];
            float gn = sd[gi + 200] + sbh[gi + 200];
            float xr = sd[gi + 300] + sbx[gi];
            float xz = sd[gi + 400] + sbx[gi + 100];
            float xn = sd[gi + 500] + sbx[gi + 200];
            float r = sigm_(xr + gr);
            float z = sigm_(xz + gz);
            float n = tanh_(xn + r * gn);
            hreg = (1.f - z) * n + z * hreg;
            sh[ge][hs] = hreg;
        }
        if (hp) *(float4*)&sctx[pe][4 * pi] = pf;
        __syncthreads();
    }

    // ---- switch input-path weights to decoder: Wc -> Wd (+Wproj rows), bc -> bd ----
    {
        if (!p1hh) {
            const float* rowB = ws + WS_WD + (r1 - H3) * H_ + 50 * l;
            #pragma unroll
            for (int j = 0; j < 25; ++j) wB[j] = *(const v2f*)(rowB + 2 * j);
        }
        if (g < 88) {
            const float* rowC = ws + WS_WD + (r2 - H3) * H_ + 50 * l;
            #pragma unroll
            for (int j = 0; j < 25; ++j) wC[j] = *(const v2f*)(rowC + 2 * j);
        } else if (g < 152) {
            const float* rowC = Wproj + (g - 88) * H_ + 50 * l;
            #pragma unroll
            for (int j = 0; j < 25; ++j) wC[j] = *(const v2f*)(rowC + 2 * j);
        }
    }
    if (tid < H3) sbx[tid] = (ws + WS_BD)[tid];
    // safe: sbx next read only after the decoder's first __syncthreads()

    // ================ decoder: outputs t = 0..256 ================
    for (int t = 0; t <= T_; ++t) {
        #pragma unroll
        for (int e = 0; e < 2; ++e) {
            v2f hv[25];
            #pragma unroll
            for (int q = 0; q < 12; ++q) {
                float4 f = *(const float4*)&sh[e][52 * l + 4 * q];
                hv[2 * q]     = v2f{f.x, f.y};
                hv[2 * q + 1] = v2f{f.z, f.w};
            }
            hv[24] = *(const v2f*)&sh[e][52 * l + 48];

            float a0 = dotred_<25>(wA, hv);
            if (wl) sdot[e][r0] = a0;
            float a1 = dotred_<25>(wB, hv);
            if (wl) sdot[e][r1] = a1;
            if (p2d) {
                float a2 = dotred_<25>(wC, hv);
                if (wl) sdot[e][r2] = a2;
            }
        }
        __syncthreads();
        if (tid >= 256 && tid < 384) {
            oute[t * O_ + oo] = sdot[oe][600 + oo] + bpr;
        }
        if (t == T_) break;   // uniform
        if (tid < 200) {
            const float* sd = sdot[ge];
            float gr = sd[gi]       + sbh[gi];
            float gz = sd[gi + 100] + sbh[gi + 100];
            float gn = sd[gi + 200] + sbh[gi + 200];
            float xr = sd[gi + 300] + sbx[gi];
            float xz = sd[gi + 400] + sbx[gi + 100];
            float xn = sd[gi + 500] + sbx[gi + 200];
            float r = sigm_(xr + gr);
            float z = sigm_(xz + gz);
            float n = tanh_(xn + r * gn);
            hreg = (1.f - z) * n + z * hreg;
            sh[ge][hs] = hreg;
        }
        __syncthreads();
    }
}

extern "C" void kernel_launch(void* const* d_in, const int* in_sizes, int n_in,
                              void* d_out, int out_size, void* d_ws, size_t ws_size,
                              hipStream_t stream) {
    (void)in_sizes; (void)n_in; (void)out_size; (void)ws_size;
    const float* ctx  = (const float*)d_in[0];
    const int*   lens = (const int*)d_in[1];
    // d_in[2] = t_steps (256, hardcoded)
    const float* Wemb = (const float*)d_in[3];
    const float* bemb = (const float*)d_in[4];
    const float* Wih  = (const float*)d_in[5];
    const float* bih  = (const float*)d_in[6];
    const float* Whh  = (const float*)d_in[7];
    const float* bhh  = (const float*)d_in[8];
    const float* Wpr  = (const float*)d_in[9];
    const float* bpr  = (const float*)d_in[10];
    float* ws  = (float*)d_ws;
    float* out = (float*)d_out;

    prep1<<<H3, 64, 0, stream>>>(Wih, bih, Wemb, bemb, ws);
    prep2<<<H3, 128, 0, stream>>>(Wpr, bpr, ws);
    sortk<<<1, 512, 0, stream>>>(lens, (int*)(ws + WS_PERM));
    rnn7<<<256, 512, 0, stream>>>(ctx, lens, Whh, bhh, Wpr, bpr, ws, out);
}

// Round 8
// 831.237 us; speedup vs baseline: 3.3272x; 1.0828x over previous
//
#include <hip/hip_runtime.h>

// SimpleARRNN: GRU encoder (len<=512) + AR decoder (257 outputs). B=512, I=64, H=100, O=64. fp32.
// Fused affine input paths: W_c = W_ih@W_embed [300x64], b_c = W_ih@b_embed + b_ih
//                           W_d = W_c@W_proj   [300x100], b_d = W_c@b_proj + b_c
// rnn8: 2 elements/block (long+short pair, length-sorted), 256 blocks x 512 threads,
// waves_per_eu(2,2) -> 256-VGPR budget (R7-proven; 124 VGPR + AGPR overflow, no scratch).
// R7 post-mortem: LDS RETURN BANDWIDTH bound (128 B/cyc/CU; wave64 b128 = 8 cyc min,
// broadcast does NOT help - per-lane bytes are the currency). R8: 4-lane row split
// (l=tid&3 owns cols 25l..25l+24; ctx-dots cols 16l..16l+15) halves per-lane hv bytes
// (200->100 B/elem) and cv bytes (128->64 B/elem). 6 passes, slot = 128p + g (g=tid>>2):
//   decoder: 0..299 Whh | 300..599 Wd | 600..663 Wproj     -> sdot[e][slot]
//   encoder: 0..299 Whh (h-dot) | 300..599 Wc (ctx-dot)    -> sdot[e][slot]
// Reduce = DPP quad_perm xor1+xor2 (involutions, verified R5/R7); lane l==0 stores.
// h in LDS: 4 chunks of 25 at stride 28 (banks 0/28/24/20 per beat - disjoint).

#define B_  512
#define LC_ 512
#define I_  64
#define H_  100
#define O_  64
#define T_  256
#define H3  300

// ws float offsets
#define WS_WC   0        // [300][64]
#define WS_BC   19200    // [300]
#define WS_WD   19500    // [300][100]
#define WS_BD   49500    // [300]
#define WS_PERM 49800    // int[512]

typedef float v2f __attribute__((ext_vector_type(2)));

__global__ __launch_bounds__(64) void prep1(const float* __restrict__ Wih,
                                            const float* __restrict__ bih,
                                            const float* __restrict__ Wemb,
                                            const float* __restrict__ bemb,
                                            float* __restrict__ ws) {
    int j = blockIdx.x;   // 0..299
    int i = threadIdx.x;  // 0..63
    float acc = 0.f;
    for (int k = 0; k < H_; ++k) acc += Wih[j * H_ + k] * Wemb[k * I_ + i];
    ws[WS_WC + j * I_ + i] = acc;
    if (i == 0) {
        float b = bih[j];
        for (int k = 0; k < H_; ++k) b += Wih[j * H_ + k] * bemb[k];
        ws[WS_BC + j] = b;
    }
}

__global__ __launch_bounds__(128) void prep2(const float* __restrict__ Wproj,
                                             const float* __restrict__ bproj,
                                             float* __restrict__ ws) {
    int j = blockIdx.x;   // 0..299
    int u = threadIdx.x;
    const float* Wc = ws + WS_WC;
    if (u < H_) {
        float acc = 0.f;
        for (int o = 0; o < O_; ++o) acc += Wc[j * I_ + o] * Wproj[o * H_ + u];
        ws[WS_WD + j * H_ + u] = acc;
    }
    if (u == 0) {
        float b = ws[WS_BC + j];
        for (int o = 0; o < O_; ++o) b += Wc[j * I_ + o] * bproj[o];
        ws[WS_BD + j] = b;
    }
}

// rank elements by length descending -> perm (longest first)
__global__ __launch_bounds__(512) void sortk(const int* __restrict__ lens,
                                             int* __restrict__ perm) {
    __shared__ int sl[B_];
    int tid = threadIdx.x;
    sl[tid] = lens[tid];
    __syncthreads();
    int li = sl[tid];
    int rank = 0;
    for (int j = 0; j < B_; ++j) {
        int lj = sl[j];
        rank += (lj > li) || (lj == li && j < tid);
    }
    perm[rank] = tid;
}

__device__ __forceinline__ float sigm_(float x) { return 1.f / (1.f + __expf(-x)); }
__device__ __forceinline__ float tanh_(float x) {
    float t = __expf(-2.f * fabsf(x));
    float r = (1.f - t) / (1.f + t);
    return (x >= 0.f) ? r : -r;
}

template <int CTRL>
__device__ __forceinline__ float dppmov_(float x) {
    return __int_as_float(
        __builtin_amdgcn_mov_dpp(__float_as_int(x), CTRL, 0xF, 0xF, true));
}
// reduce across the 4 lanes of a quad (row group); all 4 lanes end with the sum
__device__ __forceinline__ float red4_(float a) {
    a += dppmov_<0xB1>(a);    // quad_perm [1,0,3,2] = xor1 (involution, verified R5/R7)
    a += dppmov_<0x4E>(a);    // quad_perm [2,3,0,1] = xor2
    return a;
}

// h-row dot: 12 v2f pairs + tail scalar (25 cols), then quad reduce
__device__ __forceinline__ float dotH_(const v2f* __restrict__ w2, float w1,
                                       const v2f* __restrict__ hv2, float h24) {
    v2f a = {0.f, 0.f};
    #pragma unroll
    for (int j = 0; j < 12; ++j) a = w2[j] * hv2[j] + a;   // v_pk_fma_f32
    return red4_(fmaf(w1, h24, a.x + a.y));
}
// ctx-row dot: 8 v2f pairs (16 cols), then quad reduce
__device__ __forceinline__ float dotC_(const v2f* __restrict__ w2,
                                       const v2f* __restrict__ cv2) {
    v2f a = {0.f, 0.f};
    #pragma unroll
    for (int j = 0; j < 8; ++j) a = w2[j] * cv2[j] + a;
    return red4_(a.x + a.y);
}

__global__ __attribute__((amdgpu_flat_work_group_size(512, 512)))
__attribute__((amdgpu_waves_per_eu(2, 2)))
void rnn8(const float* __restrict__ ctx, const int* __restrict__ lens,
          const float* __restrict__ Whh, const float* __restrict__ bhh,
          const float* __restrict__ Wproj, const float* __restrict__ bproj,
          const float* __restrict__ ws, float* __restrict__ out) {

    const int tid = threadIdx.x;
    const int l   = tid & 3;          // quad lane: h-cols 25l.., ctx-cols 16l..
    const int g   = tid >> 2;         // 0..127 row-group
    const bool wl = (l == 0);

    const int* perm = (const int*)(ws + WS_PERM);
    const int e0 = perm[blockIdx.x];         // long element
    const int e1 = perm[511 - blockIdx.x];   // short element
    const int len0 = lens[e0], len1 = lens[e1];

    __shared__ __align__(16) float sh[2][112];    // h: 4 chunks of 25, stride 28
    __shared__ __align__(16) float sctx[2][64];
    __shared__ float sdot[2][672];                // gh 0..299 | xi 300..599 | proj 600..663
    __shared__ float sbh[H3], sbx[H3];

    // ---- per-pass config: slot = 128p + g ----
    const bool p2hh = (g < 44);      // pass2: slot 256..299 -> Whh, else input-path row g-44
    const bool p4a  = (g < 88);      // pass4 enc: Wc row 212+g; dec: Wd row 212+g (else Wproj)
    const bool p5a  = (g < 24);      // pass5 dec only: Wproj row 40+g

    // ---- register-resident weights: 6 passes x (12 v2f + tail) ----
    v2f   w2[6][12];
    float w1[6];
    {
        const float* r0 = Whh + g * H_ + 25 * l;
        const float* r1 = Whh + (128 + g) * H_ + 25 * l;
        #pragma unroll
        for (int j = 0; j < 12; ++j) {
            w2[0][j] = v2f{r0[2 * j], r0[2 * j + 1]};
            w2[1][j] = v2f{r1[2 * j], r1[2 * j + 1]};
        }
        w1[0] = r0[24]; w1[1] = r1[24];
        if (p2hh) {
            const float* r2 = Whh + (256 + g) * H_ + 25 * l;
            #pragma unroll
            for (int j = 0; j < 12; ++j) w2[2][j] = v2f{r2[2 * j], r2[2 * j + 1]};
            w1[2] = r2[24];
        } else {
            const float* r2 = ws + WS_WC + (g - 44) * I_ + 16 * l;
            #pragma unroll
            for (int j = 0; j < 8; ++j) w2[2][j] = v2f{r2[2 * j], r2[2 * j + 1]};
        }
        const float* r3 = ws + WS_WC + (84 + g) * I_ + 16 * l;
        #pragma unroll
        for (int j = 0; j < 8; ++j) w2[3][j] = v2f{r3[2 * j], r3[2 * j + 1]};
        if (p4a) {
            const float* r4 = ws + WS_WC + (212 + g) * I_ + 16 * l;
            #pragma unroll
            for (int j = 0; j < 8; ++j) w2[4][j] = v2f{r4[2 * j], r4[2 * j + 1]};
        }
    }

    // ---- roles (same as R7) ----
    const int ge = (tid >= 100);                 // gate threads: tid<200
    const int gi = tid - (ge ? 100 : 0);
    const int hs = 28 * (gi / 25) + (gi % 25);   // h slot in 28-stride chunks
    const int lenG = ge ? len1 : len0;
    float hreg = 0.f;

    const int oe = (tid >> 6) & 1;               // out threads: tid in [256,384)
    const int oo = tid & 63;
    float* oute = out + (size_t)(oe ? e1 : e0) * (T_ + 1) * O_;
    float bpr = 0.f;
    if (tid >= 256 && tid < 384) bpr = bproj[oo];

    const int pe = (tid >> 4) & 1;               // prefetch threads: tid in [384,416)
    const int pi = tid & 15;
    const float4* pctx = (const float4*)(ctx + (size_t)(pe ? e1 : e0) * LC_ * I_);
    const int lenP = pe ? len1 : len0;

    // ---- init ----
    if (tid < 224) ((float*)sh)[tid] = 0.f;
    if (tid < H3) { sbh[tid] = bhh[tid]; sbx[tid] = (ws + WS_BC)[tid]; }
    if (tid >= 384 && tid < 416) *(float4*)&sctx[pe][4 * pi] = pctx[pi];   // t=0
    __syncthreads();

    // ================ encoder: t = 0 .. len0-1 (len0 >= len1) ================
    for (int t = 0; t < len0; ++t) {
        float4 pf;
        const bool hp = (tid >= 384 && tid < 416) && (t + 1 < lenP);
        if (hp) pf = pctx[(t + 1) * 16 + pi];

        #pragma unroll
        for (int e = 0; e < 2; ++e) {
            if (e == 0 || t < len1) {       // block-uniform skip of finished element
                v2f hv2[12], cv2[8];
                float h24;
                #pragma unroll
                for (int q = 0; q < 6; ++q) {
                    float4 f = *(const float4*)&sh[e][28 * l + 4 * q];
                    hv2[2 * q]     = v2f{f.x, f.y};
                    hv2[2 * q + 1] = v2f{f.z, f.w};
                }
                h24 = sh[e][28 * l + 24];
                #pragma unroll
                for (int q = 0; q < 4; ++q) {
                    float4 f = *(const float4*)&sctx[e][16 * l + 4 * q];
                    cv2[2 * q]     = v2f{f.x, f.y};
                    cv2[2 * q + 1] = v2f{f.z, f.w};
                }

                float a0 = dotH_(w2[0], w1[0], hv2, h24);
                float a1 = dotH_(w2[1], w1[1], hv2, h24);
                float a2 = p2hh ? dotH_(w2[2], w1[2], hv2, h24) : dotC_(w2[2], cv2);
                float a3 = dotC_(w2[3], cv2);
                if (wl) {
                    sdot[e][g] = a0;
                    sdot[e][128 + g] = a1;
                    sdot[e][256 + g] = a2;
                    sdot[e][384 + g] = a3;
                }
                if (p4a) {
                    float a4 = dotC_(w2[4], cv2);
                    if (wl) sdot[e][512 + g] = a4;
                }
            }
        }
        __syncthreads();
        if (tid < 200 && t < lenG) {
            const float* sd = sdot[ge];
            float gr = sd[gi]       + sbh[gi];
            float gz = sd[gi + 100] + sbh[gi + 100];
            float gn = sd[gi + 200] + sbh[gi + 200];
            float xr = sd[gi + 300] + sbx[gi];
            float xz = sd[gi + 400] + sbx[gi + 100];
            float xn = sd[gi + 500] + sbx[gi + 200];
            float r = sigm_(xr + gr);
            float z = sigm_(xz + gz);
            float n = tanh_(xn + r * gn);
            hreg = (1.f - z) * n + z * hreg;
            sh[ge][hs] = hreg;
        }
        if (hp) *(float4*)&sctx[pe][4 * pi] = pf;
        __syncthreads();
    }

    // ---- switch input-path weights to decoder: Wd (+Wproj rows), bc -> bd ----
    {
        if (!p2hh) {
            const float* r2 = ws + WS_WD + (g - 44) * H_ + 25 * l;
            #pragma unroll
            for (int j = 0; j < 12; ++j) w2[2][j] = v2f{r2[2 * j], r2[2 * j + 1]};
            w1[2] = r2[24];
        }
        const float* r3 = ws + WS_WD + (84 + g) * H_ + 25 * l;
        #pragma unroll
        for (int j = 0; j < 12; ++j) w2[3][j] = v2f{r3[2 * j], r3[2 * j + 1]};
        w1[3] = r3[24];
        const float* r4 = p4a ? (ws + WS_WD + (212 + g) * H_ + 25 * l)
                              : (Wproj + (g - 88) * H_ + 25 * l);
        #pragma unroll
        for (int j = 0; j < 12; ++j) w2[4][j] = v2f{r4[2 * j], r4[2 * j + 1]};
        w1[4] = r4[24];
        if (p5a) {
            const float* r5 = Wproj + (40 + g) * H_ + 25 * l;
            #pragma unroll
            for (int j = 0; j < 12; ++j) w2[5][j] = v2f{r5[2 * j], r5[2 * j + 1]};
            w1[5] = r5[24];
        }
    }
    if (tid < H3) sbx[tid] = (ws + WS_BD)[tid];
    // safe: sbx next read only after the decoder's first __syncthreads()

    // ================ decoder: outputs t = 0..256 ================
    for (int t = 0; t <= T_; ++t) {
        #pragma unroll
        for (int e = 0; e < 2; ++e) {
            v2f hv2[12];
            float h24;
            #pragma unroll
            for (int q = 0; q < 6; ++q) {
                float4 f = *(const float4*)&sh[e][28 * l + 4 * q];
                hv2[2 * q]     = v2f{f.x, f.y};
                hv2[2 * q + 1] = v2f{f.z, f.w};
            }
            h24 = sh[e][28 * l + 24];

            float a0 = dotH_(w2[0], w1[0], hv2, h24);
            float a1 = dotH_(w2[1], w1[1], hv2, h24);
            float a2 = dotH_(w2[2], w1[2], hv2, h24);
            float a3 = dotH_(w2[3], w1[3], hv2, h24);
            float a4 = dotH_(w2[4], w1[4], hv2, h24);
            if (wl) {
                sdot[e][g] = a0;
                sdot[e][128 + g] = a1;
                sdot[e][256 + g] = a2;
                sdot[e][384 + g] = a3;
                sdot[e][512 + g] = a4;
            }
            if (p5a) {
                float a5 = dotH_(w2[5], w1[5], hv2, h24);
                if (wl) sdot[e][640 + g] = a5;
            }
        }
        __syncthreads();
        if (tid >= 256 && tid < 384) {
            oute[t * O_ + oo] = sdot[oe][600 + oo] + bpr;
        }
        if (t == T_) break;   // uniform
        if (tid < 200) {
            const float* sd = sdot[ge];
            float gr = sd[gi]       + sbh[gi];
            float gz = sd[gi + 100] + sbh[gi + 100];
            float gn = sd[gi + 200] + sbh[gi + 200];
            float xr = sd[gi + 300] + sbx[gi];
            float xz = sd[gi + 400] + sbx[gi + 100];
            float xn = sd[gi + 500] + sbx[gi + 200];
            float r = sigm_(xr + gr);
            float z = sigm_(xz + gz);
            float n = tanh_(xn + r * gn);
            hreg = (1.f - z) * n + z * hreg;
            sh[ge][hs] = hreg;
        }
        __syncthreads();
    }
}

extern "C" void kernel_launch(void* const* d_in, const int* in_sizes, int n_in,
                              void* d_out, int out_size, void* d_ws, size_t ws_size,
                              hipStream_t stream) {
    (void)in_sizes; (void)n_in; (void)out_size; (void)ws_size;
    const float* ctx  = (const float*)d_in[0];
    const int*   lens = (const int*)d_in[1];
    // d_in[2] = t_steps (256, hardcoded)
    const float* Wemb = (const float*)d_in[3];
    const float* bemb = (const float*)d_in[4];
    const float* Wih  = (const float*)d_in[5];
    const float* bih  = (const float*)d_in[6];
    const float* Whh  = (const float*)d_in[7];
    const float* bhh  = (const float*)d_in[8];
    const float* Wpr  = (const float*)d_in[9];
    const float* bpr  = (const float*)d_in[10];
    float* ws  = (float*)d_ws;
    float* out = (float*)d_out;

    prep1<<<H3, 64, 0, stream>>>(Wih, bih, Wemb, bemb, ws);
    prep2<<<H3, 128, 0, stream>>>(Wpr, bpr, ws);
    sortk<<<1, 512, 0, stream>>>(lens, (int*)(ws + WS_PERM));
    rnn8<<<256, 512, 0, stream>>>(ctx, lens, Whh, bhh, Wpr, bpr, ws, out);
}